// Round 3
// baseline (258.421 us; speedup 1.0000x reference)
//
#include <hip/hip_runtime.h>
#include <cstdint>

#define N_ROWS 32768
#define KDIM 1024
#define DDIM 256

typedef __attribute__((ext_vector_type(8))) short bf16x8;
typedef __attribute__((ext_vector_type(4))) float f32x4;

__device__ __forceinline__ unsigned short f2bf(float f) {
  unsigned int u = __float_as_uint(f);
  u += 0x7FFFu + ((u >> 16) & 1u);
  return (unsigned short)(u >> 16);
}
__device__ __forceinline__ float bflo(unsigned int u) { return __uint_as_float(u << 16); }
__device__ __forceinline__ float bfhi(unsigned int u) { return __uint_as_float(u & 0xFFFF0000u); }

// async global->LDS, 16B per lane. LDS dest = wave-uniform base + lane*16.
__device__ __forceinline__ void gload_lds16(const void* g, void* l) {
  __builtin_amdgcn_global_load_lds(
      (const __attribute__((address_space(1))) unsigned int*)(uintptr_t)g,
      (__attribute__((address_space(3))) unsigned int*)(unsigned int)(uintptr_t)l,
      16, 0, 0);
}

// Subtiled layouts (32-wide k-subtiles so LDS staging is contiguous and
// ds_read_b128 fragments are 2-way-conflict-free, stride 64 B):
// Xn_sub[R,k]  = (R>>7)*32768 + (k>>5)*4096 + (R&127)*32 + (k&31)
// Cn_sub[c,d]  = (c>>7)*32768 + (d>>5)*4096 + (c&127)*32 + (d&31)
// CnT_sub[c,d] = (c>>5)*8192  + d*32 + (c&31)
// P_sub[R,c]   = (R>>7)*131072 + (c>>5)*4096 + (R&127)*32 + (c&31)

// ---------------- normalize codebook -> Cn_sub, CnT_sub (bf16)
__global__ __launch_bounds__(256) void k_norm_codebook(const float* __restrict__ cb,
                                                       unsigned short* __restrict__ Cn,
                                                       unsigned short* __restrict__ CnT) {
  const int wid = threadIdx.x >> 6, lane = threadIdx.x & 63;
  const int k = blockIdx.x * 4 + wid;  // 1024 codes
  float4 v = ((const float4*)(cb + (size_t)k * DDIM))[lane];
  float s = v.x * v.x + v.y * v.y + v.z * v.z + v.w * v.w;
#pragma unroll
  for (int m = 32; m; m >>= 1) s += __shfl_xor(s, m, 64);
  const float rn = 1.0f / sqrtf(s);
  ushort4 p;
  p.x = f2bf(v.x * rn); p.y = f2bf(v.y * rn);
  p.z = f2bf(v.z * rn); p.w = f2bf(v.w * rn);
  // Cn_sub: d = lane*4 (stays within one 32-k subtile)
  const size_t cbase = (size_t)(k >> 7) * 32768 + (size_t)(k & 127) * 32;
  *(ushort4*)(Cn + cbase + (lane >> 3) * 4096 + (lane & 7) * 4) = p;
  // CnT_sub
  const size_t tbase = (size_t)(k >> 5) * 8192 + (k & 31);
  const int d = lane * 4;
  CnT[tbase + (size_t)(d + 0) * 32] = p.x;
  CnT[tbase + (size_t)(d + 1) * 32] = p.y;
  CnT[tbase + (size_t)(d + 2) * 32] = p.z;
  CnT[tbase + (size_t)(d + 3) * 32] = p.w;
}

// ---------------- normalize input rows -> Xn_sub (bf16)
__global__ __launch_bounds__(256) void k_norm_x(const float* __restrict__ x,
                                                unsigned short* __restrict__ Xn) {
  const int wid = threadIdx.x >> 6, lane = threadIdx.x & 63;
  const int R = blockIdx.x * 4 + wid;
  float4 v = ((const float4*)(x + (size_t)R * DDIM))[lane];
  float s = v.x * v.x + v.y * v.y + v.z * v.z + v.w * v.w;
#pragma unroll
  for (int m = 32; m; m >>= 1) s += __shfl_xor(s, m, 64);
  const float rn = 1.0f / sqrtf(s);
  ushort4 p;
  p.x = f2bf(v.x * rn); p.y = f2bf(v.y * rn);
  p.z = f2bf(v.z * rn); p.w = f2bf(v.w * rn);
  const size_t base = (size_t)(R >> 7) * 32768 + (size_t)(R & 127) * 32;
  *(ushort4*)(Xn + base + (lane >> 3) * 4096 + (lane & 7) * 4) = p;
}

// ---------------- logits: P = exp(Xn@Cn^T), r += rowsum(e), q += rowsum(e^2)
// Full K-extent (D=256) staged once: exactly 2 barriers in the GEMM.
__global__ __launch_bounds__(512) void k_logits(const unsigned short* __restrict__ Xn,
                                                const unsigned short* __restrict__ Cn,
                                                unsigned short* __restrict__ P,
                                                float* __restrict__ r_g,
                                                float* __restrict__ q_g) {
  __shared__ unsigned short As[32768];  // 64 KB: Xn row-tile, 8 subtiles [128][32]
  __shared__ unsigned short Bs[32768];  // 64 KB: Cn code-tile
  __shared__ float rs[128], qs[128];
  const int tid = threadIdx.x, wid = tid >> 6, lane = tid & 63;
  const int l15 = lane & 15, l4 = lane >> 4;
  const int rb = blockIdx.y, cb = blockIdx.x;
  if (tid < 128) { rs[tid] = 0.f; qs[tid] = 0.f; }
  // stage both tiles (contiguous 64 KB each)
  const char* gA = (const char*)(Xn + (size_t)rb * 32768);
  const char* gB = (const char*)(Cn + (size_t)cb * 32768);
#pragma unroll
  for (int i = 0; i < 8; ++i) {
    const int off = i * 8192 + wid * 1024 + lane * 16;
    gload_lds16(gA + off, (char*)As + off);
    gload_lds16(gB + off, (char*)Bs + off);
  }
  __syncthreads();
  const int wm = wid >> 2, wn = wid & 3;  // wave tile: 64 rows x 32 cols
  f32x4 acc[4][2] = {};
#pragma unroll
  for (int kb = 0; kb < 8; ++kb) {
    bf16x8 a[4], b[2];
#pragma unroll
    for (int mi = 0; mi < 4; ++mi)
      a[mi] = *(const bf16x8*)&As[kb * 4096 + (wm * 64 + mi * 16 + l15) * 32 + l4 * 8];
#pragma unroll
    for (int ni = 0; ni < 2; ++ni)
      b[ni] = *(const bf16x8*)&Bs[kb * 4096 + (wn * 32 + ni * 16 + l15) * 32 + l4 * 8];
#pragma unroll
    for (int mi = 0; mi < 4; ++mi)
#pragma unroll
      for (int ni = 0; ni < 2; ++ni)
        acc[mi][ni] = __builtin_amdgcn_mfma_f32_16x16x32_bf16(a[mi], b[ni], acc[mi][ni], 0, 0, 0);
  }
  // epilogue: e = exp(s) -> P_sub; r,q partials
#pragma unroll
  for (int mi = 0; mi < 4; ++mi) {
#pragma unroll
    for (int reg = 0; reg < 4; ++reg) {
      const int row = wm * 64 + mi * 16 + l4 * 4 + reg;
      float se = 0.f, sq = 0.f;
#pragma unroll
      for (int ni = 0; ni < 2; ++ni) {
        const float e = __expf(acc[mi][ni][reg]);
        se += e; sq += e * e;
        const int c = cb * 128 + wn * 32 + ni * 16 + l15;
        P[(size_t)rb * 131072 + (c >> 5) * 4096 + row * 32 + (c & 31)] = f2bf(e);
      }
#pragma unroll
      for (int m = 1; m < 16; m <<= 1) { se += __shfl_xor(se, m, 64); sq += __shfl_xor(sq, m, 64); }
      if (l15 == 0) { atomicAdd(&rs[row], se); atomicAdd(&qs[row], sq); }
    }
  }
  __syncthreads();
  if (tid < 128) {
    atomicAdd(&r_g[rb * 128 + tid], rs[tid]);
    atomicAdd(&q_g[rb * 128 + tid], qs[tid]);
  }
}

// ---------------- recon = (P @ CnT^T) * (1/r) -> fp32
__global__ __launch_bounds__(512) void k_recon(const unsigned short* __restrict__ P,
                                               const unsigned short* __restrict__ CnT,
                                               const float* __restrict__ r_g,
                                               float* __restrict__ out) {
  __shared__ unsigned short Pa[16384];  // 32 KB: P chunk [4][128][32]
  __shared__ unsigned short Bb[32768];  // 64 KB: CnT chunk [4][256][32]
  __shared__ float irl[128];
  const int tid = threadIdx.x, wid = tid >> 6, lane = tid & 63;
  const int l15 = lane & 15, l4 = lane >> 4;
  const int rb = blockIdx.x;
  if (tid < 128) irl[tid] = 1.0f / r_g[rb * 128 + tid];
  const int wm = wid >> 1, wn = wid & 1;  // wave tile: 32 rows x 128 d
  f32x4 acc[2][8] = {};
  for (int ch = 0; ch < 8; ++ch) {
    __syncthreads();
    const char* gA = (const char*)(P + (size_t)rb * 131072 + ch * 16384);
    const char* gB = (const char*)(CnT + (size_t)ch * 32768);
#pragma unroll
    for (int i = 0; i < 4; ++i) {
      const int off = i * 8192 + wid * 1024 + lane * 16;
      gload_lds16(gA + off, (char*)Pa + off);
    }
#pragma unroll
    for (int i = 0; i < 8; ++i) {
      const int off = i * 8192 + wid * 1024 + lane * 16;
      gload_lds16(gB + off, (char*)Bb + off);
    }
    __syncthreads();
#pragma unroll
    for (int kb = 0; kb < 4; ++kb) {
      bf16x8 a[2], b[8];
#pragma unroll
      for (int mi = 0; mi < 2; ++mi)
        a[mi] = *(const bf16x8*)&Pa[kb * 4096 + (wm * 32 + mi * 16 + l15) * 32 + l4 * 8];
#pragma unroll
      for (int ni = 0; ni < 8; ++ni)
        b[ni] = *(const bf16x8*)&Bb[kb * 4096 + (wn * 128 + ni * 16 + l15) * 32 + l4 * 8];
#pragma unroll
      for (int mi = 0; mi < 2; ++mi)
#pragma unroll
        for (int ni = 0; ni < 8; ++ni)
          acc[mi][ni] = __builtin_amdgcn_mfma_f32_16x16x32_bf16(a[mi], b[ni], acc[mi][ni], 0, 0, 0);
    }
  }
#pragma unroll
  for (int mi = 0; mi < 2; ++mi)
#pragma unroll
    for (int reg = 0; reg < 4; ++reg) {
      const int row = wm * 32 + mi * 16 + l4 * 4 + reg;
      const float ir = irl[row];
#pragma unroll
      for (int ni = 0; ni < 8; ++ni) {
        const int d = wn * 128 + ni * 16 + l15;
        out[(size_t)(rb * 128 + row) * DDIM + d] = acc[mi][ni][reg] * ir;
      }
    }
}

// ---------------- colsum_k = sum_i P_ik/r_i ; sLSE += series-LSE per row
__global__ __launch_bounds__(256) void k_colsum(const unsigned short* __restrict__ P,
                                                const float* __restrict__ r_g,
                                                const float* __restrict__ q_g,
                                                float* __restrict__ colsum,
                                                float* __restrict__ sLSE) {
  __shared__ float irl[128];
  const int tid = threadIdx.x;
  const int rb = blockIdx.x;
  if (tid < 128) {
    const float ir = 1.0f / r_g[rb * 128 + tid];
    irl[tid] = ir;
    float lse = logf((float)(KDIM + 1) + 0.5f * q_g[rb * 128 + tid] * ir * ir);
#pragma unroll
    for (int m = 32; m; m >>= 1) lse += __shfl_xor(lse, m, 64);
    if ((tid & 63) == 0) atomicAdd(sLSE, lse);
  }
  __syncthreads();
  const int kb = tid >> 3, st = tid & 7;
  const int c8 = (st & 3) * 8, rpar = st >> 2;
  const unsigned short* base = P + (size_t)rb * 131072 + kb * 4096 + c8;
  float cs[8];
#pragma unroll
  for (int j = 0; j < 8; ++j) cs[j] = 0.f;
  for (int it = 0; it < 64; ++it) {
    const int row = it * 2 + rpar;
    const uint4 q = *(const uint4*)(base + (size_t)row * 32);
    const float ir = irl[row];
    float f[8];
    f[0] = bflo(q.x); f[1] = bfhi(q.x); f[2] = bflo(q.y); f[3] = bfhi(q.y);
    f[4] = bflo(q.z); f[5] = bfhi(q.z); f[6] = bflo(q.w); f[7] = bfhi(q.w);
#pragma unroll
    for (int j = 0; j < 8; ++j) cs[j] += f[j] * ir;
  }
#pragma unroll
  for (int j = 0; j < 8; ++j) cs[j] += __shfl_xor(cs[j], 4, 64);
  if (rpar == 0) {
#pragma unroll
    for (int j = 0; j < 8; ++j) atomicAdd(&colsum[kb * 32 + c8 + j], cs[j]);
  }
}

// ---------------- finalize loss
__global__ __launch_bounds__(256) void k_final(const float* __restrict__ colsum,
                                               const float* __restrict__ sLSE,
                                               float* __restrict__ out) {
  __shared__ float r1[256], r2[256];
  const int tid = threadIdx.x;
  float s1 = 0.f, s2 = 0.f;
  for (int j = tid; j < KDIM; j += 256) {
    const float v = colsum[j];
    s1 += v;
    s2 += v * v;
  }
  r1[tid] = s1; r2[tid] = s2;
  __syncthreads();
  for (int o = 128; o; o >>= 1) {
    if (tid < o) { r1[tid] += r1[tid + o]; r2[tid] += r2[tid + o]; }
    __syncthreads();
  }
  if (tid == 0) {
    const double S = r1[0];
    const double Q = r2[0];
    const double L = sLSE[0];
    const double entropy = (S * L - Q) / (double)N_ROWS;
    const double l1 = S / ((double)N_ROWS * (double)KDIM);
    out[(size_t)N_ROWS * DDIM] = (float)(1000.0 * l1 + 5e-5 * entropy);
  }
}

extern "C" void kernel_launch(void* const* d_in, const int* in_sizes, int n_in,
                              void* d_out, int out_size, void* d_ws, size_t ws_size,
                              hipStream_t stream) {
  const float* x = (const float*)d_in[0];   // [8,4096,256] fp32
  const float* cb = (const float*)d_in[1];  // [1024,256] fp32
  float* out = (float*)d_out;               // recon [8388608] + loss [1]
  char* ws = (char*)d_ws;

  float* r_g          = (float*)(ws + 0);          // 131072 B
  float* q_g          = (float*)(ws + 131072);     // 131072 B
  float* colsum       = (float*)(ws + 262144);     // 4096 B
  float* sLSE         = (float*)(ws + 266240);     // 256 B
  unsigned short* Cn  = (unsigned short*)(ws + 266496);    // 524288 B (subtiled)
  unsigned short* CnT = (unsigned short*)(ws + 790784);    // 524288 B (subtiled)
  unsigned short* Xn  = (unsigned short*)(ws + 1315072);   // 16777216 B (subtiled)
  unsigned short* P   = (unsigned short*)(ws + 18092288);  // 67108864 B (subtiled)

  hipMemsetAsync(ws, 0, 266496, stream);  // zero r_g, q_g, colsum, sLSE
  k_norm_codebook<<<256, 256, 0, stream>>>(cb, Cn, CnT);
  k_norm_x<<<8192, 256, 0, stream>>>(x, Xn);
  k_logits<<<dim3(8, 256), 512, 0, stream>>>(Xn, Cn, P, r_g, q_g);
  k_recon<<<256, 512, 0, stream>>>(P, CnT, r_g, out);
  k_colsum<<<256, 256, 0, stream>>>(P, r_g, q_g, colsum, sLSE);
  k_final<<<1, 256, 0, stream>>>(colsum, sLSE, out);
}

// Round 4
// 233.479 us; speedup vs baseline: 1.1068x; 1.1068x over previous
//
#include <hip/hip_runtime.h>
#include <cstdint>

#define N_ROWS 32768
#define KDIM 1024
#define DDIM 256

typedef __attribute__((ext_vector_type(8))) short bf16x8;
typedef __attribute__((ext_vector_type(4))) float f32x4;

__device__ __forceinline__ unsigned short f2bf(float f) {
  unsigned int u = __float_as_uint(f);
  u += 0x7FFFu + ((u >> 16) & 1u);
  return (unsigned short)(u >> 16);
}

// async global->LDS, 16B per lane. LDS dest = wave-uniform base + lane*16.
__device__ __forceinline__ void gload_lds16(const void* g, void* l) {
  __builtin_amdgcn_global_load_lds(
      (const __attribute__((address_space(1))) unsigned int*)(uintptr_t)g,
      (__attribute__((address_space(3))) unsigned int*)(unsigned int)(uintptr_t)l,
      16, 0, 0);
}

// Layouts (u16 offsets), all with XOR chunk swizzle baked in (chunk = 8 u16 = 16 B):
// Cn64 [t=c>>6][kb=d>>5][c&63][32]: off = t*16384 + kb*2048 + (c&63)*32 + ((((d&31)>>3)^(c&3))*8) + (d&7)
// CnT  [s=c>>5][d][32]:            off = s*8192 + d*32 + ((((c&31)>>3)^(d&3))*8) + (c&7)
// Xn   [T=r>>7][kb=k>>5][r&127][32]: off = T*32768 + kb*4096 + (r&127)*32 + ((((k&31)>>3)^(r&3))*8) + (k&7)
// Fragment reads use chunk = l4 ^ (row&3) -> 2-way bank aliasing only (free).

// ---------------- normalize codebook -> Cn64, CnT (bf16, swizzled layouts)
__global__ __launch_bounds__(256) void k_norm_cb(const float* __restrict__ cb,
                                                 unsigned short* __restrict__ Cn,
                                                 unsigned short* __restrict__ CnT) {
  const int wid = threadIdx.x >> 6, lane = threadIdx.x & 63;
  const int k = blockIdx.x * 4 + wid;  // 1024 codes
  float4 v = ((const float4*)(cb + (size_t)k * DDIM))[lane];
  float s = v.x * v.x + v.y * v.y + v.z * v.z + v.w * v.w;
#pragma unroll
  for (int m = 32; m; m >>= 1) s += __shfl_xor(s, m, 64);
  const float rn = 1.0f / sqrtf(s);
  ushort4 p;
  p.x = f2bf(v.x * rn); p.y = f2bf(v.y * rn);
  p.z = f2bf(v.z * rn); p.w = f2bf(v.w * rn);
  // Cn64: d = lane*4 (8-B aligned within a 16-B chunk)
  const int kb = lane >> 3;
  const int physA = ((lane & 7) >> 1) ^ (k & 3);
  *(ushort4*)(Cn + (size_t)(k >> 6) * 16384 + kb * 2048 + (k & 63) * 32 + physA * 8 + (lane & 1) * 4) = p;
  // CnT: 4 scalar u16 stores, row = d, xor chunk by (d&3)=j
  const int sgl = k >> 5, c31 = k & 31, ch = c31 >> 3, cw = c31 & 7;
  const unsigned short pv[4] = {p.x, p.y, p.z, p.w};
#pragma unroll
  for (int j = 0; j < 4; ++j) {
    const int d = lane * 4 + j;
    CnT[(size_t)sgl * 8192 + d * 32 + ((ch ^ j) * 8) + cw] = pv[j];
  }
}

// ---------------- k_r: normalize X (emit Xn bf16), S-GEMM full K=1024,
// keep only r=rowsum(exp), q=rowsum(exp^2) -> r_g, series-LSE -> sLSE.
// Double-buffered 32-KB Cn stages, 1 barrier per K-tile.
__global__ __launch_bounds__(512, 2) void k_r(const float* __restrict__ x,
                                              const unsigned short* __restrict__ Cn,
                                              unsigned short* __restrict__ Xn_g,
                                              float* __restrict__ r_g,
                                              float* __restrict__ sLSE) {
  __shared__ unsigned short Xs[32768];      // 64 KB [kb][128][32] swizzled
  __shared__ unsigned short Cb[2][16384];   // 2 x 32 KB
  __shared__ float rs[128], qs[128];
  const int tid = threadIdx.x, wid = tid >> 6, lane = tid & 63;
  const int l15 = lane & 15, l4 = lane >> 4;
  const int rb = blockIdx.x;  // 256 blocks x 128 rows
  if (tid < 128) { rs[tid] = 0.f; qs[tid] = 0.f; }
  // stage Cn tile 0 early (overlaps the norm phase)
#pragma unroll
  for (int i = 0; i < 4; ++i) {
    const int off = i * 8192 + wid * 1024 + lane * 16;
    gload_lds16((const char*)Cn + off, (char*)Cb[0] + off);
  }
  // norm: one wave per row, 16 passes
#pragma unroll
  for (int p16 = 0; p16 < 16; ++p16) {
    const int row = p16 * 8 + wid;
    float4 v = ((const float4*)(x + (size_t)(rb * 128 + row) * DDIM))[lane];
    float s = v.x * v.x + v.y * v.y + v.z * v.z + v.w * v.w;
#pragma unroll
    for (int m = 32; m; m >>= 1) s += __shfl_xor(s, m, 64);
    const float rn = 1.0f / sqrtf(s);
    ushort4 p;
    p.x = f2bf(v.x * rn); p.y = f2bf(v.y * rn);
    p.z = f2bf(v.z * rn); p.w = f2bf(v.w * rn);
    const int phys = ((lane & 7) >> 1) ^ (row & 3);
    const int uoff = (lane >> 3) * 4096 + row * 32 + phys * 8 + (lane & 1) * 4;
    *(ushort4*)&Xs[uoff] = p;
    *(ushort4*)(Xn_g + (size_t)rb * 32768 + uoff) = p;
  }
  const int wm = wid >> 1, wn = wid & 1;  // wave: 32 rows x 32 cols
  float se[2][4], sq[2][4];
#pragma unroll
  for (int mi = 0; mi < 2; ++mi)
#pragma unroll
    for (int reg = 0; reg < 4; ++reg) { se[mi][reg] = 0.f; sq[mi][reg] = 0.f; }
  const int xsw = l4 ^ (l15 & 3);
  for (int kt = 0; kt < 16; ++kt) {
    __syncthreads();
    if (kt < 15) {
#pragma unroll
      for (int i = 0; i < 4; ++i) {
        const int off = i * 8192 + wid * 1024 + lane * 16;
        gload_lds16((const char*)Cn + (size_t)(kt + 1) * 32768 + off, (char*)Cb[(kt + 1) & 1] + off);
      }
    }
    const unsigned short* B = Cb[kt & 1];
    f32x4 acc[2][2] = {};
#pragma unroll
    for (int kb = 0; kb < 8; ++kb) {
      bf16x8 a[2], b[2];
#pragma unroll
      for (int mi = 0; mi < 2; ++mi)
        a[mi] = *(const bf16x8*)&Xs[kb * 4096 + (wm * 32 + mi * 16 + l15) * 32 + xsw * 8];
#pragma unroll
      for (int ni = 0; ni < 2; ++ni)
        b[ni] = *(const bf16x8*)&B[kb * 2048 + (wn * 32 + ni * 16 + l15) * 32 + xsw * 8];
#pragma unroll
      for (int mi = 0; mi < 2; ++mi)
#pragma unroll
        for (int ni = 0; ni < 2; ++ni)
          acc[mi][ni] = __builtin_amdgcn_mfma_f32_16x16x32_bf16(a[mi], b[ni], acc[mi][ni], 0, 0, 0);
    }
#pragma unroll
    for (int mi = 0; mi < 2; ++mi)
#pragma unroll
      for (int reg = 0; reg < 4; ++reg)
#pragma unroll
        for (int ni = 0; ni < 2; ++ni) {
          const float e = __expf(acc[mi][ni][reg]);
          se[mi][reg] += e; sq[mi][reg] += e * e;
        }
  }
  // reduce over l15, combine wn pairs via LDS
#pragma unroll
  for (int mi = 0; mi < 2; ++mi)
#pragma unroll
    for (int reg = 0; reg < 4; ++reg) {
#pragma unroll
      for (int m = 1; m < 16; m <<= 1) {
        se[mi][reg] += __shfl_xor(se[mi][reg], m, 64);
        sq[mi][reg] += __shfl_xor(sq[mi][reg], m, 64);
      }
    }
  if (l15 == 0) {
#pragma unroll
    for (int mi = 0; mi < 2; ++mi)
#pragma unroll
      for (int reg = 0; reg < 4; ++reg) {
        const int row = wm * 32 + mi * 16 + l4 * 4 + reg;
        atomicAdd(&rs[row], se[mi][reg]);
        atomicAdd(&qs[row], sq[mi][reg]);
      }
  }
  __syncthreads();
  if (tid < 128) {
    const float r = rs[tid];
    const float ir = 1.0f / r;
    r_g[rb * 128 + tid] = r;
    float lse = logf((float)(KDIM + 1) + 0.5f * qs[tid] * ir * ir);
#pragma unroll
    for (int m = 32; m; m >>= 1) lse += __shfl_xor(lse, m, 64);
    if ((tid & 63) == 0) atomicAdd(sLSE, lse);
  }
}

// ---------------- k_main: recompute S per kt (64 codes), exp -> Ps (LDS, swizzled),
// colsum via global atomics, PV: O += Ps @ CnT -> out*(1/r).
__global__ __launch_bounds__(512, 2) void k_main(const unsigned short* __restrict__ Xn_g,
                                                 const unsigned short* __restrict__ Cn,
                                                 const unsigned short* __restrict__ CnT,
                                                 const float* __restrict__ r_g,
                                                 float* __restrict__ colsum_g,
                                                 float* __restrict__ out) {
  __shared__ unsigned short Xs[32768];  // 64 KB
  __shared__ unsigned short CA[16384];  // 32 KB: Cn(kt)
  __shared__ unsigned short CB[16384];  // 32 KB: CnT(kt)
  __shared__ unsigned short Ps[8192];   // 16 KB: [128][64] swizzled
  const int tid = threadIdx.x, wid = tid >> 6, lane = tid & 63;
  const int l15 = lane & 15, l4 = lane >> 4;
  const int rb = blockIdx.x;
  // stage Xn tile (64 KB) + CA(0)
#pragma unroll
  for (int i = 0; i < 8; ++i) {
    const int off = i * 8192 + wid * 1024 + lane * 16;
    gload_lds16((const char*)Xn_g + (size_t)rb * 65536 + off, (char*)Xs + off);
  }
#pragma unroll
  for (int i = 0; i < 4; ++i) {
    const int off = i * 8192 + wid * 1024 + lane * 16;
    gload_lds16((const char*)Cn + off, (char*)CA + off);
  }
  const int wm = wid >> 1, wn = wid & 1;
  float ir[2][4];
#pragma unroll
  for (int mi = 0; mi < 2; ++mi)
#pragma unroll
    for (int reg = 0; reg < 4; ++reg)
      ir[mi][reg] = 1.0f / r_g[rb * 128 + wm * 32 + mi * 16 + l4 * 4 + reg];
  f32x4 O[2][8] = {};
  const int xsw = l4 ^ (l15 & 3);
  const int psw_r = l15 >> 1;  // Ps read xor
  __syncthreads();
  for (int kt = 0; kt < 16; ++kt) {
    // stage CnT(kt) into CB -- overlaps S-MFMA
#pragma unroll
    for (int i = 0; i < 4; ++i) {
      const int off = i * 8192 + wid * 1024 + lane * 16;
      gload_lds16((const char*)CnT + (size_t)kt * 32768 + off, (char*)CB + off);
    }
    f32x4 S[2][2] = {};
#pragma unroll
    for (int kb = 0; kb < 8; ++kb) {
      bf16x8 a[2], b[2];
#pragma unroll
      for (int mi = 0; mi < 2; ++mi)
        a[mi] = *(const bf16x8*)&Xs[kb * 4096 + (wm * 32 + mi * 16 + l15) * 32 + xsw * 8];
#pragma unroll
      for (int ni = 0; ni < 2; ++ni)
        b[ni] = *(const bf16x8*)&CA[kb * 2048 + (wn * 32 + ni * 16 + l15) * 32 + xsw * 8];
#pragma unroll
      for (int mi = 0; mi < 2; ++mi)
#pragma unroll
        for (int ni = 0; ni < 2; ++ni)
          S[mi][ni] = __builtin_amdgcn_mfma_f32_16x16x32_bf16(a[mi], b[ni], S[mi][ni], 0, 0, 0);
    }
    // epilogue: exp -> Ps; colsum partial
    float cs[2] = {0.f, 0.f};
#pragma unroll
    for (int mi = 0; mi < 2; ++mi)
#pragma unroll
      for (int reg = 0; reg < 4; ++reg) {
        const int row = wm * 32 + mi * 16 + l4 * 4 + reg;
        const int pswz = (l4 * 2 + (reg >> 1)) & 7;  // ((row&15)>>1)
#pragma unroll
        for (int ni = 0; ni < 2; ++ni) {
          const float e = __expf(S[mi][ni][reg]);
          const int chl = wn * 4 + ni * 2 + (l15 >> 3);
          Ps[row * 64 + ((chl ^ pswz) * 8) + (l15 & 7)] = f2bf(e);
          cs[ni] += e * ir[mi][reg];
        }
      }
#pragma unroll
    for (int ni = 0; ni < 2; ++ni) {
      float v = cs[ni];
      v += __shfl_xor(v, 16, 64);
      v += __shfl_xor(v, 32, 64);
      if (lane < 16) atomicAdd(&colsum_g[kt * 64 + wn * 32 + ni * 16 + l15], v);
    }
    __syncthreads();  // Ps visible; CB staged; CA reads done
    if (kt < 15) {
#pragma unroll
      for (int i = 0; i < 4; ++i) {
        const int off = i * 8192 + wid * 1024 + lane * 16;
        gload_lds16((const char*)Cn + (size_t)(kt + 1) * 32768 + off, (char*)CA + off);
      }
    }
    // PV: O += Ps @ CnT  (A rows = i, B rows = d)
#pragma unroll
    for (int kb2 = 0; kb2 < 2; ++kb2) {
      bf16x8 a2[2], b2[8];
#pragma unroll
      for (int mi = 0; mi < 2; ++mi) {
        const int row = wm * 32 + mi * 16 + l15;
        a2[mi] = *(const bf16x8*)&Ps[row * 64 + (((kb2 * 4 + l4) ^ psw_r) * 8)];
      }
#pragma unroll
      for (int ni = 0; ni < 8; ++ni) {
        const int d = wn * 128 + ni * 16 + l15;
        b2[ni] = *(const bf16x8*)&CB[kb2 * 8192 + d * 32 + xsw * 8];
      }
#pragma unroll
      for (int mi = 0; mi < 2; ++mi)
#pragma unroll
        for (int ni = 0; ni < 8; ++ni)
          O[mi][ni] = __builtin_amdgcn_mfma_f32_16x16x32_bf16(a2[mi], b2[ni], O[mi][ni], 0, 0, 0);
    }
    __syncthreads();  // Ps/CB reads done; CA(kt+1) staged
  }
  // out = O * ir
#pragma unroll
  for (int mi = 0; mi < 2; ++mi)
#pragma unroll
    for (int reg = 0; reg < 4; ++reg) {
      const int row = wm * 32 + mi * 16 + l4 * 4 + reg;
      const float irv = ir[mi][reg];
#pragma unroll
      for (int ni = 0; ni < 8; ++ni) {
        const int d = wn * 128 + ni * 16 + l15;
        out[(size_t)(rb * 128 + row) * DDIM + d] = O[mi][ni][reg] * irv;
      }
    }
}

// ---------------- finalize loss
__global__ __launch_bounds__(256) void k_final(const float* __restrict__ colsum,
                                               const float* __restrict__ sLSE,
                                               float* __restrict__ out) {
  __shared__ float r1[256], r2[256];
  const int tid = threadIdx.x;
  float s1 = 0.f, s2 = 0.f;
  for (int j = tid; j < KDIM; j += 256) {
    const float v = colsum[j];
    s1 += v;
    s2 += v * v;
  }
  r1[tid] = s1; r2[tid] = s2;
  __syncthreads();
  for (int o = 128; o; o >>= 1) {
    if (tid < o) { r1[tid] += r1[tid + o]; r2[tid] += r2[tid + o]; }
    __syncthreads();
  }
  if (tid == 0) {
    const double S = r1[0];
    const double Q = r2[0];
    const double L = sLSE[0];
    const double entropy = (S * L - Q) / (double)N_ROWS;
    const double l1 = S / ((double)N_ROWS * (double)KDIM);
    out[(size_t)N_ROWS * DDIM] = (float)(1000.0 * l1 + 5e-5 * entropy);
  }
}

extern "C" void kernel_launch(void* const* d_in, const int* in_sizes, int n_in,
                              void* d_out, int out_size, void* d_ws, size_t ws_size,
                              hipStream_t stream) {
  const float* x = (const float*)d_in[0];   // [8,4096,256] fp32
  const float* cb = (const float*)d_in[1];  // [1024,256] fp32
  float* out = (float*)d_out;               // recon [8388608] + loss [1]
  char* ws = (char*)d_ws;

  float* colsum       = (float*)(ws + 0);          // 4096 B
  float* sLSE         = (float*)(ws + 4096);       // 256 B (uses 4)
  unsigned short* Cn  = (unsigned short*)(ws + 4352);      // 524288 B (Cn64 swizzled)
  unsigned short* CnT = (unsigned short*)(ws + 528640);    // 524288 B (CnT swizzled)
  unsigned short* Xn  = (unsigned short*)(ws + 1052928);   // 16777216 B (Xn swizzled)
  float* r_g          = (float*)(ws + 17830144);   // 131072 B

  hipMemsetAsync(ws, 0, 4352, stream);  // zero colsum + sLSE
  k_norm_cb<<<256, 256, 0, stream>>>(cb, Cn, CnT);
  k_r<<<256, 512, 0, stream>>>(x, Cn, Xn, r_g, sLSE);
  k_main<<<256, 512, 0, stream>>>(Xn, Cn, CnT, r_g, colsum, out);
  k_final<<<1, 256, 0, stream>>>(colsum, sLSE, out);
}

// Round 5
// 167.417 us; speedup vs baseline: 1.5436x; 1.3946x over previous
//
#include <hip/hip_runtime.h>
#include <cstdint>

#define N_ROWS 32768
#define KDIM 1024
#define DDIM 256

typedef __attribute__((ext_vector_type(8))) short bf16x8;
typedef __attribute__((ext_vector_type(4))) float f32x4;

__device__ __forceinline__ unsigned short f2bf(float f) {
  unsigned int u = __float_as_uint(f);
  u += 0x7FFFu + ((u >> 16) & 1u);
  return (unsigned short)(u >> 16);
}

// async global->LDS, 16B per lane. LDS dest = wave-uniform base + lane*16.
__device__ __forceinline__ void gload_lds16(const void* g, void* l) {
  __builtin_amdgcn_global_load_lds(
      (const __attribute__((address_space(1))) unsigned int*)(uintptr_t)g,
      (__attribute__((address_space(3))) unsigned int*)(unsigned int)(uintptr_t)l,
      16, 0, 0);
}

// Layouts (u16 offsets), XOR chunk swizzle baked in (chunk = 8 u16 = 16 B):
// Cn64 [t=c>>6][kb=d>>5][c&63][32]: off = t*16384 + kb*2048 + (c&63)*32 + ((((d&31)>>3)^(c&3))*8) + (d&7)
// CnT  [s=c>>5][d][32]:            off = s*8192 + d*32 + ((((c&31)>>3)^(d&3))*8) + (c&7)
// Fragment reads use chunk = l4 ^ (row&3) -> 2-way bank aliasing only (free).

// ---------------- normalize codebook -> Cn64, CnT (bf16, swizzled)
__global__ __launch_bounds__(256) void k_norm_cb(const float* __restrict__ cb,
                                                 unsigned short* __restrict__ Cn,
                                                 unsigned short* __restrict__ CnT) {
  const int wid = threadIdx.x >> 6, lane = threadIdx.x & 63;
  const int k = blockIdx.x * 4 + wid;  // 1024 codes
  float4 v = ((const float4*)(cb + (size_t)k * DDIM))[lane];
  float s = v.x * v.x + v.y * v.y + v.z * v.z + v.w * v.w;
#pragma unroll
  for (int m = 32; m; m >>= 1) s += __shfl_xor(s, m, 64);
  const float rn = 1.0f / sqrtf(s);
  ushort4 p;
  p.x = f2bf(v.x * rn); p.y = f2bf(v.y * rn);
  p.z = f2bf(v.z * rn); p.w = f2bf(v.w * rn);
  const int kb = lane >> 3;
  const int physA = ((lane & 7) >> 1) ^ (k & 3);
  *(ushort4*)(Cn + (size_t)(k >> 6) * 16384 + kb * 2048 + (k & 63) * 32 + physA * 8 + (lane & 1) * 4) = p;
  const int sgl = k >> 5, c31 = k & 31, ch = c31 >> 3, cw = c31 & 7;
  const unsigned short pv[4] = {p.x, p.y, p.z, p.w};
#pragma unroll
  for (int j = 0; j < 4; ++j) {
    const int d = lane * 4 + j;
    CnT[(size_t)sgl * 8192 + d * 32 + ((ch ^ j) * 8) + cw] = pv[j];
  }
}

// ---------------- k_all: one block = 128 rows, everything fused.
// Pass A: S-GEMM (full K), keep r=rowsum(exp), q=rowsum(exp^2) -> series-LSE.
// Pass B: recompute S per kt, exp->Ps(LDS), colsum->LDS, PV -> out*(1/r).
// colsum partials: plain per-block stores, reduced in k_final (no global atomics).
__global__ __launch_bounds__(512, 2) void k_all(const float* __restrict__ x,
                                                const unsigned short* __restrict__ Cn,
                                                const unsigned short* __restrict__ CnT,
                                                float* __restrict__ part,
                                                float* __restrict__ lse_part,
                                                float* __restrict__ out) {
  __shared__ unsigned short Xs[32768];      // 64 KB [kb][128][32] swizzled
  __shared__ unsigned short CAb[2][16384];  // 2 x 32 KB
  __shared__ unsigned short Ps[128 * 72];   // 18 KB, stride 72 (16B-aligned, bank-spread)
  __shared__ float csl[1024];
  __shared__ float rs[128], qs[128], irl[128];
  __shared__ float lse_sh[2];

  const int tid = threadIdx.x, wid = tid >> 6, lane = tid & 63;
  const int l15 = lane & 15, l4 = lane >> 4;
  const int rb = blockIdx.x;  // 256 blocks x 128 rows
  if (tid < 128) { rs[tid] = 0.f; qs[tid] = 0.f; }
  for (int j = tid; j < 1024; j += 512) csl[j] = 0.f;

  // stage Cn tile 0 early (overlaps norm phase)
#pragma unroll
  for (int i = 0; i < 4; ++i) {
    const int off = i * 8192 + wid * 1024 + lane * 16;
    gload_lds16((const char*)Cn + off, (char*)CAb[0] + off);
  }
  // norm: one wave per row, 16 passes
#pragma unroll
  for (int p16 = 0; p16 < 16; ++p16) {
    const int row = p16 * 8 + wid;
    float4 v = ((const float4*)(x + (size_t)(rb * 128 + row) * DDIM))[lane];
    float s = v.x * v.x + v.y * v.y + v.z * v.z + v.w * v.w;
#pragma unroll
    for (int m = 32; m; m >>= 1) s += __shfl_xor(s, m, 64);
    const float rn = 1.0f / sqrtf(s);
    ushort4 p;
    p.x = f2bf(v.x * rn); p.y = f2bf(v.y * rn);
    p.z = f2bf(v.z * rn); p.w = f2bf(v.w * rn);
    const int phys = ((lane & 7) >> 1) ^ (row & 3);
    *(ushort4*)&Xs[(lane >> 3) * 4096 + row * 32 + phys * 8 + (lane & 1) * 4] = p;
  }

  const int wm = wid >> 1, wn = wid & 1;  // wave: 32 rows x (32 cols S / 128 d PV)
  const int xsw = l4 ^ (l15 & 3);

  // ---------------- Pass A: r, q ----------------
  float se[2][4], sq[2][4];
#pragma unroll
  for (int mi = 0; mi < 2; ++mi)
#pragma unroll
    for (int reg = 0; reg < 4; ++reg) { se[mi][reg] = 0.f; sq[mi][reg] = 0.f; }
  for (int kt = 0; kt < 16; ++kt) {
    __syncthreads();
    const int ktn = (kt + 1) & 15;  // kt=15 restages tile 0 for pass B
#pragma unroll
    for (int i = 0; i < 4; ++i) {
      const int off = i * 8192 + wid * 1024 + lane * 16;
      gload_lds16((const char*)Cn + (size_t)ktn * 32768 + off, (char*)CAb[(kt + 1) & 1] + off);
    }
    const unsigned short* B = CAb[kt & 1];
    f32x4 acc[2][2] = {};
#pragma unroll
    for (int kb = 0; kb < 8; ++kb) {
      bf16x8 a[2], b[2];
#pragma unroll
      for (int mi = 0; mi < 2; ++mi)
        a[mi] = *(const bf16x8*)&Xs[kb * 4096 + (wm * 32 + mi * 16 + l15) * 32 + xsw * 8];
#pragma unroll
      for (int ni = 0; ni < 2; ++ni)
        b[ni] = *(const bf16x8*)&B[kb * 2048 + (wn * 32 + ni * 16 + l15) * 32 + xsw * 8];
#pragma unroll
      for (int mi = 0; mi < 2; ++mi)
#pragma unroll
        for (int ni = 0; ni < 2; ++ni)
          acc[mi][ni] = __builtin_amdgcn_mfma_f32_16x16x32_bf16(a[mi], b[ni], acc[mi][ni], 0, 0, 0);
    }
#pragma unroll
    for (int mi = 0; mi < 2; ++mi)
#pragma unroll
      for (int reg = 0; reg < 4; ++reg)
#pragma unroll
        for (int ni = 0; ni < 2; ++ni) {
          const float e = __expf(acc[mi][ni][reg]);
          se[mi][reg] += e; sq[mi][reg] += e * e;
        }
  }
#pragma unroll
  for (int mi = 0; mi < 2; ++mi)
#pragma unroll
    for (int reg = 0; reg < 4; ++reg) {
#pragma unroll
      for (int m = 1; m < 16; m <<= 1) {
        se[mi][reg] += __shfl_xor(se[mi][reg], m, 64);
        sq[mi][reg] += __shfl_xor(sq[mi][reg], m, 64);
      }
    }
  if (l15 == 0) {
#pragma unroll
    for (int mi = 0; mi < 2; ++mi)
#pragma unroll
      for (int reg = 0; reg < 4; ++reg) {
        const int row = wm * 32 + mi * 16 + l4 * 4 + reg;
        atomicAdd(&rs[row], se[mi][reg]);
        atomicAdd(&qs[row], sq[mi][reg]);
      }
  }
  __syncthreads();
  if (tid < 128) {
    const float r = rs[tid];
    const float ir = 1.0f / r;
    irl[tid] = ir;
    // series-LSE: sum_k exp(e_k/r) = K + 1 + q/(2 r^2)  (|d|~1e-3, err ~1e-9)
    float lse = logf((float)(KDIM + 1) + 0.5f * qs[tid] * ir * ir);
#pragma unroll
    for (int m = 32; m; m >>= 1) lse += __shfl_xor(lse, m, 64);
    if ((tid & 63) == 0) lse_sh[tid >> 6] = lse;
  }
  __syncthreads();
  float ir[2][4];
#pragma unroll
  for (int mi = 0; mi < 2; ++mi)
#pragma unroll
    for (int reg = 0; reg < 4; ++reg)
      ir[mi][reg] = irl[wm * 32 + mi * 16 + l4 * 4 + reg];

  // ---------------- Pass B: recompute S, colsum, PV ----------------
  f32x4 O[2][8] = {};
  const int psw_r = l15 >> 1;
  for (int kt = 0; kt < 16; ++kt) {
    // stage CnT(kt) -> CAb[1] (overlaps S-MFMA)
#pragma unroll
    for (int i = 0; i < 4; ++i) {
      const int off = i * 8192 + wid * 1024 + lane * 16;
      gload_lds16((const char*)CnT + (size_t)kt * 32768 + off, (char*)CAb[1] + off);
    }
    f32x4 S[2][2] = {};
#pragma unroll
    for (int kb = 0; kb < 8; ++kb) {
      bf16x8 a[2], b[2];
#pragma unroll
      for (int mi = 0; mi < 2; ++mi)
        a[mi] = *(const bf16x8*)&Xs[kb * 4096 + (wm * 32 + mi * 16 + l15) * 32 + xsw * 8];
#pragma unroll
      for (int ni = 0; ni < 2; ++ni)
        b[ni] = *(const bf16x8*)&CAb[0][kb * 2048 + (wn * 32 + ni * 16 + l15) * 32 + xsw * 8];
#pragma unroll
      for (int mi = 0; mi < 2; ++mi)
#pragma unroll
        for (int ni = 0; ni < 2; ++ni)
          S[mi][ni] = __builtin_amdgcn_mfma_f32_16x16x32_bf16(a[mi], b[ni], S[mi][ni], 0, 0, 0);
    }
    // epilogue: exp -> Ps (stride 72); colsum partials -> LDS (4-way atomics)
    float cs[2] = {0.f, 0.f};
#pragma unroll
    for (int mi = 0; mi < 2; ++mi)
#pragma unroll
      for (int reg = 0; reg < 4; ++reg) {
        const int row = wm * 32 + mi * 16 + l4 * 4 + reg;
        const int pswz = (l4 * 2 + (reg >> 1)) & 7;  // ((row&15)>>1)
#pragma unroll
        for (int ni = 0; ni < 2; ++ni) {
          const float e = __expf(S[mi][ni][reg]);
          const int chl = wn * 4 + ni * 2 + (l15 >> 3);
          Ps[row * 72 + ((chl ^ pswz) * 8) + (l15 & 7)] = f2bf(e);
          cs[ni] += e * ir[mi][reg];
        }
      }
#pragma unroll
    for (int ni = 0; ni < 2; ++ni) {
      float v = cs[ni];
      v += __shfl_xor(v, 16, 64);
      v += __shfl_xor(v, 32, 64);
      if (lane < 16) atomicAdd(&csl[kt * 64 + wn * 32 + ni * 16 + l15], v);
    }
    __syncthreads();  // CnT staged; Ps visible; CAb[0] reads done
    if (kt < 15) {
#pragma unroll
      for (int i = 0; i < 4; ++i) {
        const int off = i * 8192 + wid * 1024 + lane * 16;
        gload_lds16((const char*)Cn + (size_t)(kt + 1) * 32768 + off, (char*)CAb[0] + off);
      }
    }
    // PV: O += Ps @ CnT
#pragma unroll
    for (int kb2 = 0; kb2 < 2; ++kb2) {
      bf16x8 a2[2], b2[8];
#pragma unroll
      for (int mi = 0; mi < 2; ++mi) {
        const int row = wm * 32 + mi * 16 + l15;
        a2[mi] = *(const bf16x8*)&Ps[row * 72 + (((kb2 * 4 + l4) ^ psw_r) * 8)];
      }
#pragma unroll
      for (int ni = 0; ni < 8; ++ni) {
        const int d = wn * 128 + ni * 16 + l15;
        b2[ni] = *(const bf16x8*)&CAb[1][kb2 * 8192 + d * 32 + xsw * 8];
      }
#pragma unroll
      for (int mi = 0; mi < 2; ++mi)
#pragma unroll
        for (int ni = 0; ni < 8; ++ni)
          O[mi][ni] = __builtin_amdgcn_mfma_f32_16x16x32_bf16(a2[mi], b2[ni], O[mi][ni], 0, 0, 0);
    }
    __syncthreads();  // Ps/CAb[1] reads done; Cn(kt+1) staged
  }

  // out = O * ir
#pragma unroll
  for (int mi = 0; mi < 2; ++mi)
#pragma unroll
    for (int reg = 0; reg < 4; ++reg) {
      const int row = wm * 32 + mi * 16 + l4 * 4 + reg;
      const float irv = ir[mi][reg];
#pragma unroll
      for (int ni = 0; ni < 8; ++ni) {
        const int d = wn * 128 + ni * 16 + l15;
        out[(size_t)(rb * 128 + row) * DDIM + d] = O[mi][ni][reg] * irv;
      }
    }
  // colsum partials: plain coalesced stores (no atomics)
  for (int j = tid; j < 1024; j += 512) part[rb * 1024 + j] = csl[j];
  if (tid == 0) lse_part[rb] = lse_sh[0] + lse_sh[1];
}

// ---------------- finalize: reduce 256 partials, compute loss
__global__ __launch_bounds__(1024) void k_final(const float* __restrict__ part,
                                                const float* __restrict__ lse_part,
                                                float* __restrict__ out) {
  __shared__ float sh1[16], sh2[16], shl[16];
  const int tid = threadIdx.x, lane = tid & 63, w = tid >> 6;
  float cs = 0.f;
  for (int b = 0; b < 256; ++b) cs += part[b * 1024 + tid];
  float s1 = cs, s2 = cs * cs;
  float sl = (tid < 256) ? lse_part[tid] : 0.f;
#pragma unroll
  for (int m = 32; m; m >>= 1) {
    s1 += __shfl_xor(s1, m, 64);
    s2 += __shfl_xor(s2, m, 64);
    sl += __shfl_xor(sl, m, 64);
  }
  if (lane == 0) { sh1[w] = s1; sh2[w] = s2; shl[w] = sl; }
  __syncthreads();
  if (tid == 0) {
    double S = 0.0, Q = 0.0, L = 0.0;
    for (int i = 0; i < 16; ++i) { S += sh1[i]; Q += sh2[i]; L += shl[i]; }
    const double entropy = (S * L - Q) / (double)N_ROWS;
    const double l1 = S / ((double)N_ROWS * (double)KDIM);
    out[(size_t)N_ROWS * DDIM] = (float)(1000.0 * l1 + 5e-5 * entropy);
  }
}

extern "C" void kernel_launch(void* const* d_in, const int* in_sizes, int n_in,
                              void* d_out, int out_size, void* d_ws, size_t ws_size,
                              hipStream_t stream) {
  const float* x = (const float*)d_in[0];   // [8,4096,256] fp32
  const float* cb = (const float*)d_in[1];  // [1024,256] fp32
  float* out = (float*)d_out;               // recon [8388608] + loss [1]
  char* ws = (char*)d_ws;

  unsigned short* Cn  = (unsigned short*)(ws + 0);         // 524288 B (Cn64 swizzled)
  unsigned short* CnT = (unsigned short*)(ws + 524288);    // 524288 B (CnT swizzled)
  float* part         = (float*)(ws + 1048576);            // 1048576 B (256 x 1024)
  float* lse_part     = (float*)(ws + 2097152);            // 1024 B

  k_norm_cb<<<256, 256, 0, stream>>>(cb, Cn, CnT);
  k_all<<<256, 512, 0, stream>>>(x, Cn, CnT, part, lse_part, out);
  k_final<<<1, 1024, 0, stream>>>(part, lse_part, out);
}

// Round 6
// 155.074 us; speedup vs baseline: 1.6664x; 1.0796x over previous
//
#include <hip/hip_runtime.h>
#include <cstdint>

#define N_ROWS 32768
#define KDIM 1024
#define DDIM 256

typedef __attribute__((ext_vector_type(8))) short bf16x8;
typedef __attribute__((ext_vector_type(4))) float f32x4;

__device__ __forceinline__ unsigned short f2bf(float f) {
  unsigned int u = __float_as_uint(f);
  u += 0x7FFFu + ((u >> 16) & 1u);
  return (unsigned short)(u >> 16);
}

// async global->LDS, 16B per lane. LDS dest = wave-uniform base + lane*16.
__device__ __forceinline__ void gload_lds16(const void* g, void* l) {
  __builtin_amdgcn_global_load_lds(
      (const __attribute__((address_space(1))) unsigned int*)(uintptr_t)g,
      (__attribute__((address_space(3))) unsigned int*)(unsigned int)(uintptr_t)l,
      16, 0, 0);
}

// Global layouts (u16 offsets), XOR chunk swizzle baked in (chunk = 8 u16 = 16 B):
// Cn64 [t=c>>6][kb=d>>5][c&63][32]: off = t*16384 + kb*2048 + (c&63)*32 + ((((d&31)>>3)^(c&3))*8) + (d&7)
// CnT  [s=c>>5][d][32]:            off = s*8192 + d*32 + ((((c&31)>>3)^(d&3))*8) + (c&7)
// Fragment reads use chunk = l4 ^ (l15&3) -> 2-way bank aliasing only (free).

// ---------------- normalize codebook -> Cn64, CnT (bf16, swizzled)
__global__ __launch_bounds__(256) void k_norm_cb(const float* __restrict__ cb,
                                                 unsigned short* __restrict__ Cn,
                                                 unsigned short* __restrict__ CnT) {
  const int wid = threadIdx.x >> 6, lane = threadIdx.x & 63;
  const int k = blockIdx.x * 4 + wid;  // 1024 codes
  float4 v = ((const float4*)(cb + (size_t)k * DDIM))[lane];
  float s = v.x * v.x + v.y * v.y + v.z * v.z + v.w * v.w;
#pragma unroll
  for (int m = 32; m; m >>= 1) s += __shfl_xor(s, m, 64);
  const float rn = 1.0f / sqrtf(s);
  ushort4 p;
  p.x = f2bf(v.x * rn); p.y = f2bf(v.y * rn);
  p.z = f2bf(v.z * rn); p.w = f2bf(v.w * rn);
  const int kb = lane >> 3;
  const int physA = ((lane & 7) >> 1) ^ (k & 3);
  *(ushort4*)(Cn + (size_t)(k >> 6) * 16384 + kb * 2048 + (k & 63) * 32 + physA * 8 + (lane & 1) * 4) = p;
  const int sgl = k >> 5, c31 = k & 31, ch = c31 >> 3, cw = c31 & 7;
  const unsigned short pv[4] = {p.x, p.y, p.z, p.w};
#pragma unroll
  for (int j = 0; j < 4; ++j) {
    const int d = lane * 4 + j;
    CnT[(size_t)sgl * 8192 + d * 32 + ((ch ^ j) * 8) + cw] = pv[j];
  }
}

// ---------------- k_all: one block = 128 rows.
// A-fragments (32 rows x 256 k per wave) live in registers for both passes.
// LDS: 4-slot ring of 32-KB code tiles; prefetch issued right after each barrier.
// Pass A: S-GEMM full K -> r=rowsum(exp), q=rowsum(exp^2) -> series-LSE.
// Pass B: recompute S per kt(64 codes), exp->Ps(LDS), colsum->LDS, PV -> out*(1/r).
__global__ __launch_bounds__(512, 2) void k_all(const float* __restrict__ x,
                                                const unsigned short* __restrict__ Cn,
                                                const unsigned short* __restrict__ CnT,
                                                float* __restrict__ part,
                                                float* __restrict__ lse_part,
                                                float* __restrict__ out) {
  __shared__ unsigned short Cb[4][16384];   // 128 KB ring; Cb[0..1] doubles as Xs transient
  __shared__ unsigned short Ps[128 * 72];   // 18 KB, stride 72 (16B-aligned, bank-spread)
  __shared__ float csl[1024];
  __shared__ float rs[128], qs[128], irl[128];
  __shared__ float lse_sh[2];

  const int tid = threadIdx.x, wid = tid >> 6, lane = tid & 63;
  const int l15 = lane & 15, l4 = lane >> 4;
  const int wm = wid >> 1, wn = wid & 1;  // wave: 32 rows x (32 cols S / 128 d PV)
  const int rb = blockIdx.x;              // 256 blocks x 128 rows
  if (tid < 128) { rs[tid] = 0.f; qs[tid] = 0.f; }
  for (int j = tid; j < 1024; j += 512) csl[j] = 0.f;

  // early stage: Cn[0]->Cb[2], Cn[1]->Cb[3] (overlaps norm phase)
#pragma unroll
  for (int i = 0; i < 4; ++i) {
    const int off = i * 8192 + wid * 1024 + lane * 16;
    gload_lds16((const char*)Cn + off, (char*)Cb[2] + off);
    gload_lds16((const char*)Cn + 32768 + off, (char*)Cb[3] + off);
  }

  // norm: one wave per row, 16 passes -> Xs (= Cb[0..1] region, plain layout)
  unsigned short* Xs = &Cb[0][0];
#pragma unroll
  for (int p16 = 0; p16 < 16; ++p16) {
    const int row = p16 * 8 + wid;
    float4 v = ((const float4*)(x + (size_t)(rb * 128 + row) * DDIM))[lane];
    float s = v.x * v.x + v.y * v.y + v.z * v.z + v.w * v.w;
#pragma unroll
    for (int m = 32; m; m >>= 1) s += __shfl_xor(s, m, 64);
    const float rn = 1.0f / sqrtf(s);
    ushort4 p;
    p.x = f2bf(v.x * rn); p.y = f2bf(v.y * rn);
    p.z = f2bf(v.z * rn); p.w = f2bf(v.w * rn);
    *(ushort4*)&Xs[(lane >> 3) * 4096 + row * 32 + (lane & 7) * 4] = p;
  }
  __syncthreads();
  // A-fragments -> registers (one-time; Xs region is then recycled by the ring)
  bf16x8 areg[2][8];
#pragma unroll
  for (int mi = 0; mi < 2; ++mi)
#pragma unroll
    for (int kb = 0; kb < 8; ++kb)
      areg[mi][kb] = *(const bf16x8*)&Xs[kb * 4096 + (wm * 32 + mi * 16 + l15) * 32 + l4 * 8];

  const int xsw = l4 ^ (l15 & 3);

  // ---------------- Pass A: r, q ----------------
  float se[2][4], sq[2][4];
#pragma unroll
  for (int mi = 0; mi < 2; ++mi)
#pragma unroll
    for (int reg = 0; reg < 4; ++reg) { se[mi][reg] = 0.f; sq[mi][reg] = 0.f; }
  for (int kt = 0; kt < 16; ++kt) {
    __syncthreads();  // stage(kt) complete; areg reads done (kt=0); ring reuse safe
    // issue prefetch for kt+2 (tail: Cn[0], CnT[0] for pass B)
    {
      const char* src = (kt <= 13) ? (const char*)Cn + (size_t)(kt + 2) * 32768
                      : (kt == 14) ? (const char*)Cn
                                   : (const char*)CnT;
      char* dst = (char*)Cb[kt & 3];
#pragma unroll
      for (int i = 0; i < 4; ++i) {
        const int off = i * 8192 + wid * 1024 + lane * 16;
        gload_lds16(src + off, dst + off);
      }
    }
    const unsigned short* B = Cb[(kt + 2) & 3];
    f32x4 acc[2][2] = {};
#pragma unroll
    for (int kb = 0; kb < 8; ++kb) {
      bf16x8 b[2];
#pragma unroll
      for (int ni = 0; ni < 2; ++ni)
        b[ni] = *(const bf16x8*)&B[kb * 2048 + (wn * 32 + ni * 16 + l15) * 32 + xsw * 8];
#pragma unroll
      for (int mi = 0; mi < 2; ++mi)
#pragma unroll
        for (int ni = 0; ni < 2; ++ni)
          acc[mi][ni] = __builtin_amdgcn_mfma_f32_16x16x32_bf16(areg[mi][kb], b[ni], acc[mi][ni], 0, 0, 0);
    }
#pragma unroll
    for (int mi = 0; mi < 2; ++mi)
#pragma unroll
      for (int reg = 0; reg < 4; ++reg)
#pragma unroll
        for (int ni = 0; ni < 2; ++ni) {
          const float e = __expf(acc[mi][ni][reg]);
          se[mi][reg] += e; sq[mi][reg] += e * e;
        }
  }
#pragma unroll
  for (int mi = 0; mi < 2; ++mi)
#pragma unroll
    for (int reg = 0; reg < 4; ++reg) {
#pragma unroll
      for (int m = 1; m < 16; m <<= 1) {
        se[mi][reg] += __shfl_xor(se[mi][reg], m, 64);
        sq[mi][reg] += __shfl_xor(sq[mi][reg], m, 64);
      }
    }
  if (l15 == 0) {
#pragma unroll
    for (int mi = 0; mi < 2; ++mi)
#pragma unroll
      for (int reg = 0; reg < 4; ++reg) {
        const int row = wm * 32 + mi * 16 + l4 * 4 + reg;
        atomicAdd(&rs[row], se[mi][reg]);
        atomicAdd(&qs[row], sq[mi][reg]);
      }
  }
  __syncthreads();  // also drains pass-A tail stages (Cn[0],CnT[0])
  if (tid < 128) {
    const float r = rs[tid];
    const float ir = 1.0f / r;
    irl[tid] = ir;
    // series-LSE: sum_k exp(e_k/r) = K + 1 + q/(2 r^2)  (|d|~1e-3, err ~1e-9)
    float lse = logf((float)(KDIM + 1) + 0.5f * qs[tid] * ir * ir);
#pragma unroll
    for (int m = 32; m; m >>= 1) lse += __shfl_xor(lse, m, 64);
    if ((tid & 63) == 0) lse_sh[tid >> 6] = lse;
  }
  __syncthreads();
  float ir[2][4];
#pragma unroll
  for (int mi = 0; mi < 2; ++mi)
#pragma unroll
    for (int reg = 0; reg < 4; ++reg)
      ir[mi][reg] = irl[wm * 32 + mi * 16 + l4 * 4 + reg];

  // ---------------- Pass B: recompute S, colsum, PV ----------------
  f32x4 O[2][8] = {};
  const int psw_r = l15 >> 1;
  for (int kt = 0; kt < 16; ++kt) {
    const int cslot = (kt & 1) ? 0 : 2;   // Cn(kt)
    const int tslot = cslot | 1;          // CnT(kt)
    const int nslot = (kt & 1) ? 2 : 0;   // target pair for kt+1
    if (kt < 15) {  // stage Cn[kt+1] (full S window to complete)
#pragma unroll
      for (int i = 0; i < 4; ++i) {
        const int off = i * 8192 + wid * 1024 + lane * 16;
        gload_lds16((const char*)Cn + (size_t)(kt + 1) * 32768 + off, (char*)Cb[nslot] + off);
      }
    }
    f32x4 S[2][2] = {};
#pragma unroll
    for (int kb = 0; kb < 8; ++kb) {
      bf16x8 b[2];
#pragma unroll
      for (int ni = 0; ni < 2; ++ni)
        b[ni] = *(const bf16x8*)&Cb[cslot][kb * 2048 + (wn * 32 + ni * 16 + l15) * 32 + xsw * 8];
#pragma unroll
      for (int mi = 0; mi < 2; ++mi)
#pragma unroll
        for (int ni = 0; ni < 2; ++ni)
          S[mi][ni] = __builtin_amdgcn_mfma_f32_16x16x32_bf16(areg[mi][kb], b[ni], S[mi][ni], 0, 0, 0);
    }
    // epilogue: exp -> Ps (stride 72, swizzled); colsum partials
    float cs[2] = {0.f, 0.f};
#pragma unroll
    for (int mi = 0; mi < 2; ++mi)
#pragma unroll
      for (int reg = 0; reg < 4; ++reg) {
        const int row = wm * 32 + mi * 16 + l4 * 4 + reg;
        const int pswz = (l4 * 2 + (reg >> 1)) & 7;  // ((row&15)>>1)
#pragma unroll
        for (int ni = 0; ni < 2; ++ni) {
          const float e = __expf(S[mi][ni][reg]);
          const int chl = wn * 4 + ni * 2 + (l15 >> 3);
          Ps[row * 72 + ((chl ^ pswz) * 8) + (l15 & 7)] = f2bf(e);
          cs[ni] += e * ir[mi][reg];
        }
      }
#pragma unroll
    for (int ni = 0; ni < 2; ++ni) {
      float v = cs[ni];
      v += __shfl_xor(v, 16, 64);
      v += __shfl_xor(v, 32, 64);
      if (lane < 16) atomicAdd(&csl[kt * 64 + wn * 32 + ni * 16 + l15], v);
    }
    __syncthreads();  // Ps visible; Cn[kt+1] drained (had S window)
    if (kt < 15) {  // stage CnT[kt+1] (PV window to complete)
#pragma unroll
      for (int i = 0; i < 4; ++i) {
        const int off = i * 8192 + wid * 1024 + lane * 16;
        gload_lds16((const char*)CnT + (size_t)(kt + 1) * 32768 + off, (char*)Cb[nslot + 1] + off);
      }
    }
    // PV: O += Ps @ CnT
#pragma unroll
    for (int kb2 = 0; kb2 < 2; ++kb2) {
      bf16x8 a2[2], b2[8];
#pragma unroll
      for (int mi = 0; mi < 2; ++mi) {
        const int row = wm * 32 + mi * 16 + l15;
        a2[mi] = *(const bf16x8*)&Ps[row * 72 + (((kb2 * 4 + l4) ^ psw_r) * 8)];
      }
#pragma unroll
      for (int ni = 0; ni < 8; ++ni) {
        const int d = wn * 128 + ni * 16 + l15;
        b2[ni] = *(const bf16x8*)&Cb[tslot][kb2 * 8192 + d * 32 + xsw * 8];
      }
#pragma unroll
      for (int mi = 0; mi < 2; ++mi)
#pragma unroll
        for (int ni = 0; ni < 8; ++ni)
          O[mi][ni] = __builtin_amdgcn_mfma_f32_16x16x32_bf16(a2[mi], b2[ni], O[mi][ni], 0, 0, 0);
    }
    __syncthreads();  // Ps reuse safe; CnT[kt+1] drained (had PV window)
  }

  // out = O * ir
#pragma unroll
  for (int mi = 0; mi < 2; ++mi)
#pragma unroll
    for (int reg = 0; reg < 4; ++reg) {
      const int row = wm * 32 + mi * 16 + l4 * 4 + reg;
      const float irv = ir[mi][reg];
#pragma unroll
      for (int ni = 0; ni < 8; ++ni) {
        const int d = wn * 128 + ni * 16 + l15;
        out[(size_t)(rb * 128 + row) * DDIM + d] = O[mi][ni][reg] * irv;
      }
    }
  // colsum partials: plain coalesced stores (no global atomics)
  for (int j = tid; j < 1024; j += 512) part[rb * 1024 + j] = csl[j];
  if (tid == 0) lse_part[rb] = lse_sh[0] + lse_sh[1];
}

// ---------------- parallel reduce: 64 blocks x 16 k-columns each
__global__ __launch_bounds__(256) void k_final(const float* __restrict__ part,
                                               const float* __restrict__ lse_part,
                                               float* __restrict__ acc3) {
  __shared__ float sh1[4], sh2[4], shl[4];
  const int tid = threadIdx.x, lane = tid & 63, w = tid >> 6;
  const int bh = tid & 15;   // b-group (16 blocks each)
  const int kh = tid >> 4;   // 0..15
  const int k = blockIdx.x * 16 + kh;
  float s = 0.f;
#pragma unroll
  for (int m = 0; m < 16; ++m) s += part[(size_t)(bh * 16 + m) * 1024 + k];
#pragma unroll
  for (int m = 1; m < 16; m <<= 1) s += __shfl_xor(s, m, 64);
  float s1 = ((lane & 15) == 0) ? s : 0.f;
  float s2 = ((lane & 15) == 0) ? s * s : 0.f;
  s1 += __shfl_xor(s1, 16, 64); s2 += __shfl_xor(s2, 16, 64);
  s1 += __shfl_xor(s1, 32, 64); s2 += __shfl_xor(s2, 32, 64);
  if (lane == 0) { sh1[w] = s1; sh2[w] = s2; }
  float l = 0.f;
  if (blockIdx.x == 0) {
    l = lse_part[tid];
#pragma unroll
    for (int m = 1; m < 64; m <<= 1) l += __shfl_xor(l, m, 64);
  }
  if (lane == 0) shl[w] = l;
  __syncthreads();
  if (tid == 0) {
    atomicAdd(&acc3[0], sh1[0] + sh1[1] + sh1[2] + sh1[3]);
    atomicAdd(&acc3[1], sh2[0] + sh2[1] + sh2[2] + sh2[3]);
    if (blockIdx.x == 0) atomicAdd(&acc3[2], shl[0] + shl[1] + shl[2] + shl[3]);
  }
}

// ---------------- final loss
__global__ __launch_bounds__(64) void k_loss(const float* __restrict__ acc3,
                                             float* __restrict__ out) {
  if (threadIdx.x == 0) {
    const double S = acc3[0];          // sum of all distances (~N)
    const double Q = acc3[1];          // ||colsum||^2
    const double L = acc3[2];          // sum_i LSE_i
    const double entropy = (S * L - Q) / (double)N_ROWS;
    const double l1 = S / ((double)N_ROWS * (double)KDIM);
    out[(size_t)N_ROWS * DDIM] = (float)(1000.0 * l1 + 5e-5 * entropy);
  }
}

extern "C" void kernel_launch(void* const* d_in, const int* in_sizes, int n_in,
                              void* d_out, int out_size, void* d_ws, size_t ws_size,
                              hipStream_t stream) {
  const float* x = (const float*)d_in[0];   // [8,4096,256] fp32
  const float* cb = (const float*)d_in[1];  // [1024,256] fp32
  float* out = (float*)d_out;               // recon [8388608] + loss [1]
  char* ws = (char*)d_ws;

  unsigned short* Cn  = (unsigned short*)(ws + 0);         // 524288 B (Cn64 swizzled)
  unsigned short* CnT = (unsigned short*)(ws + 524288);    // 524288 B (CnT swizzled)
  float* part         = (float*)(ws + 1048576);            // 1048576 B (256 x 1024)
  float* lse_part     = (float*)(ws + 2097152);            // 1024 B
  float* acc3         = (float*)(ws + 2098176);            // 16 B

  hipMemsetAsync(acc3, 0, 16, stream);
  k_norm_cb<<<256, 256, 0, stream>>>(cb, Cn, CnT);
  k_all<<<256, 512, 0, stream>>>(x, Cn, CnT, part, lse_part, out);
  k_final<<<64, 256, 0, stream>>>(part, lse_part, acc3);
  k_loss<<<1, 64, 0, stream>>>(acc3, out);
}